// Round 10
// baseline (428.443 us; speedup 1.0000x reference)
//
#include <hip/hip_runtime.h>
#include <hip/hip_fp16.h>
#include <math.h>

typedef _Float16 half_t;
typedef _Float16 h8_t __attribute__((ext_vector_type(8)));
typedef _Float16 h4_t __attribute__((ext_vector_type(4)));
typedef float f4_t __attribute__((ext_vector_type(4)));
typedef float f16x __attribute__((ext_vector_type(16)));

#define MFMA32(a, b, c) __builtin_amdgcn_mfma_f32_32x32x16_f16(a, b, c, 0, 0, 0)

static constexpr int kB = 4;
static constexpr int kS = 2048;
static constexpr int kD = 1024;
static constexpr int BM = 128;
static constexpr int BN = 128;
static constexpr int BK = 32;   // LDS leading dim (halves): 64B rows, lane-contiguous
static constexpr int NT = 512;  // 8 waves/block: 64x32 output sub-tile per wave

// ---------- async 16B global->LDS (gfx950 direct-to-LDS path) ----------
__device__ __forceinline__ void gload16(const half_t* g, half_t* l) {
  __builtin_amdgcn_global_load_lds(
      (const __attribute__((address_space(1))) void*)g,
      (__attribute__((address_space(3))) void*)l, 16, 0, 0);
}

// ---------- stage one BMxBK fp16 tile into LDS [BM][BK], bank-swizzled ----------
// 512 threads: thread t covers row r = t>>2, 16B granule (t&3).
// LDS dest stays LINEAR (global_load_lds: wave base + lane*16B); the global
// SOURCE column is XOR-swizzled by ((r>>1)&3) granules, and fragment reads
// apply the same XOR (2-way bank aliasing = free; was 8-way).
__device__ __forceinline__ void stage_tile(half_t* __restrict__ sm,
                                           const half_t* __restrict__ g, int ld) {
  const int t = threadIdx.x;
  const int r = t >> 2;
  const int g8 = (t & 3) * 8;
  const int c = g8 ^ (((r >> 1) & 3) << 3);  // pre-swizzled source col
  gload16(&g[(size_t)r * ld + c], &sm[r * BK + g8]);
}

template <bool SPLIT>
__device__ __forceinline__ void stage_all(half_t* buf, const half_t* Ahi,
                                          const half_t* Alo, int lda,
                                          const half_t* Bhi, const half_t* Blo,
                                          int ldb, size_t ko) {
  stage_tile(buf, Ahi + ko, lda);
  stage_tile(buf + BM * BK, Bhi + ko, ldb);
  if (SPLIT) {
    stage_tile(buf + 2 * BM * BK, Alo + ko, lda);
    stage_tile(buf + 3 * BM * BK, Blo + ko, ldb);
  }
}

// ---------- NT GEMM core, 8-wave, 2-phase dbuf, 32x32x16 MFMA ----------
// C[128,128] += A[128,K] * B[128,K]^T, optional hi/lo split (3-term product).
// Wave wid owns rows [(wid>>2)*64, +64) x cols [(wid&3)*32, +32): two 32x32
// accs. 32x32x16 runs ~15-20% faster per FLOP than 16x16x32 (2382 vs 2075 TF
// ubench) and halves the MFMA instruction count: 12 big vs 24 small per
// K-step, same 12 ds_read_b128.
// Fragment layout (CDNA convention, mirrors the verified 16x16 mapping):
//   A: row = lane&31, k = (lane>>5)*8 + j   (8 halves, 16B read)
//   B: col = lane&31, k = (lane>>5)*8 + j
//   C/D: col = lane&31, row = (reg&3) + 8*(reg>>2) + 4*(lane>>5)
template <bool SPLIT>
__device__ __forceinline__ void gemm_core(const half_t* __restrict__ Ahi,
                                          const half_t* __restrict__ Alo, int lda,
                                          const half_t* __restrict__ Bhi,
                                          const half_t* __restrict__ Blo, int ldb,
                                          int k_iters, half_t* sm, f16x (&acc)[2]) {
  constexpr int BUFSZ = (SPLIT ? 4 : 2) * BM * BK;
  const int lane = threadIdx.x & 63;
  const int wid = threadIdx.x >> 6;        // 0..7
  const int wm = (wid >> 2) * 64;          // 0, 64
  const int wn = (wid & 3) * 32;           // 0, 32, 64, 96
  const int r32 = lane & 31;               // row (A) / col (B) within 32-tile
  const int hi = lane >> 5;                // k-granule select
  const int key = (r32 >> 1) & 3;          // LDS swizzle key (row bits 1-2)

  half_t* cur = sm;
  half_t* nxt = sm + BUFSZ;

  stage_all<SPLIT>(cur, Ahi, Alo, lda, Bhi, Blo, ldb, 0);
  asm volatile("s_waitcnt vmcnt(0)" ::: "memory");
  __builtin_amdgcn_s_barrier();

  for (int kk = 0; kk < k_iters; ++kk) {
    if (kk + 1 < k_iters)
      stage_all<SPLIT>(nxt, Ahi, Alo, lda, Bhi, Blo, ldb, (size_t)(kk + 1) * BK);
    const half_t* sAh = cur;
    const half_t* sBh = cur + BM * BK;
    const half_t* sAl = cur + 2 * BM * BK;
    const half_t* sBl = cur + 3 * BM * BK;
    h8_t a[2][2], al[2][2], b[2], bl[2];  // [slice][row-tile] / [slice]
#pragma unroll
    for (int s = 0; s < 2; ++s) {
      const int off = ((s * 2 + hi) ^ key) * 8;  // swizzled k-offset (halves)
#pragma unroll
      for (int t = 0; t < 2; ++t) {
        a[s][t] = *(const h8_t*)&sAh[(wm + t * 32 + r32) * BK + off];
        if (SPLIT) al[s][t] = *(const h8_t*)&sAl[(wm + t * 32 + r32) * BK + off];
      }
      b[s] = *(const h8_t*)&sBh[(wn + r32) * BK + off];
      if (SPLIT) bl[s] = *(const h8_t*)&sBl[(wn + r32) * BK + off];
    }
#pragma unroll
    for (int s = 0; s < 2; ++s)
#pragma unroll
      for (int t = 0; t < 2; ++t) {
        acc[t] = MFMA32(a[s][t], b[s], acc[t]);
        if (SPLIT) {
          acc[t] = MFMA32(a[s][t], bl[s], acc[t]);
          acc[t] = MFMA32(al[s][t], b[s], acc[t]);
        }
      }
    asm volatile("s_waitcnt vmcnt(0)" ::: "memory");
    __builtin_amdgcn_s_barrier();
    half_t* t = cur; cur = nxt; nxt = t;
  }
}

// ---------- merged Q = X*WQK^T (split) + V = X*WOV^T (plain), 1024 blocks ----------
// One launch fills the machine with MIXED work: q-blocks' vmcnt drains hide
// under v-blocks' MFMAs and vice versa (proven R8: 100us vs ~125 serial).
__global__ __launch_bounds__(NT) void gemm_qv_kernel(
    const half_t* __restrict__ Xhi, const half_t* __restrict__ Xlo,
    const half_t* __restrict__ Whi, const half_t* __restrict__ Wlo,
    const half_t* __restrict__ WVh,
    half_t* __restrict__ Qhi, half_t* __restrict__ Qlo,
    half_t* __restrict__ Vt) {
  __shared__ half_t sm[2 * 4 * BM * BK];  // 64 KB (q path; v uses first 32 KB)
  const int b = blockIdx.x;                     // 0..1023
  const int swz = (b & 7) * 128 + (b >> 3);     // XCD-contiguous chunks
  const bool isq = swz < 512;
  const int w = isq ? swz : swz - 512;          // 64 row-tiles x 8 col-tiles
  const size_t arow = (size_t)(w >> 3) * BM;
  const size_t brow = (size_t)(w & 7) * BN;

  const int lane = threadIdx.x & 63;
  const int wid = threadIdx.x >> 6;
  const int wm = (wid >> 2) * 64, wn = (wid & 3) * 32;
  const int r32 = lane & 31, hi = lane >> 5;

  if (isq) {
    f16x acc[2] = {};
    gemm_core<true>(Xhi + arow * kD, Xlo + arow * kD, kD,
                    Whi + brow * kD, Wlo + brow * kD, kD, kD / BK, sm, acc);
#pragma unroll
    for (int t = 0; t < 2; ++t)
#pragma unroll
      for (int g = 0; g < 16; ++g) {
        const int rl = (g & 3) + 8 * (g >> 2) + 4 * hi;
        const size_t row = arow + wm + t * 32 + rl;
        const size_t col = brow + wn + r32;
        const float q = acc[t][g];
        const half_t qh = (half_t)q;
        const half_t ql = (half_t)(q - (float)qh);
        const size_t idx = row * kD + col;
        Qhi[idx] = qh;
        Qlo[idx] = ql;
      }
  } else {
    f16x acc[2] = {};
    gemm_core<false>(Xhi + arow * kD, nullptr, kD,
                     WVh + brow * kD, nullptr, kD, kD / BK, sm, acc);
#pragma unroll
    for (int t = 0; t < 2; ++t)
#pragma unroll
      for (int g = 0; g < 16; ++g) {
        const int rl = (g & 3) + 8 * (g >> 2) + 4 * hi;
        const size_t row = arow + wm + t * 32 + rl;   // global 0..8191
        const size_t col = brow + wn + r32;           // e: 0..1023
        const size_t bi = row >> 11;
        const size_t s = row & 2047;
        Vt[bi * (size_t)kD * kS + col * kS + s] = (half_t)acc[t][g];
      }
  }
}

// ---------- Sc = 32 * Q * X^T (2D grid, early-return, no swizzle) ----------
__global__ __launch_bounds__(NT) void gemm_score_kernel(
    const half_t* __restrict__ Qhi, const half_t* __restrict__ Qlo,
    const half_t* __restrict__ Xhi, const half_t* __restrict__ Xlo,
    float* __restrict__ Sc) {
  const int tn = blockIdx.x, tm = blockIdx.y, bi = blockIdx.z;
  if (tn > tm) return;  // fully masked tile: softmax never reads it
  __shared__ half_t sm[2 * 4 * BM * BK];  // 64 KB
  const size_t arow = (size_t)bi * kS + (size_t)tm * BM;
  const size_t brow = (size_t)bi * kS + (size_t)tn * BN;
  f16x acc[2] = {};
  gemm_core<true>(Qhi + arow * kD, Qlo + arow * kD, kD,
                  Xhi + brow * kD, Xlo + brow * kD, kD, kD / BK, sm, acc);
  float* out = Sc + (size_t)bi * kS * kS;
  const int lane = threadIdx.x & 63;
  const int wid = threadIdx.x >> 6;
  const int wm = (wid >> 2) * 64, wn = (wid & 3) * 32;
  const int r32 = lane & 31, hi = lane >> 5;
#pragma unroll
  for (int t = 0; t < 2; ++t)
#pragma unroll
    for (int g = 0; g < 16; ++g) {
      const int rl = (g & 3) + 8 * (g >> 2) + 4 * hi;
      const int row = tm * BM + wm + t * 32 + rl;
      const int col = tn * BN + wn + r32;
      out[(size_t)row * kS + col] = 32.0f * acc[t][g];
    }
}

// ---------- row softmax (causal), causal-prefix reads, vectorized I/O ----------
__global__ __launch_bounds__(256) void softmax_kernel(float* __restrict__ A,
                                                      half_t* __restrict__ Ah) {
  const int rgl = blockIdx.x;  // 0..8191
  const int s = rgl & 2047;
  float* row = A + (size_t)rgl * kS;
  half_t* hrow = Ah + (size_t)rgl * kS;
  const int tid = threadIdx.x;
  const int n = s + 1;
  const int base = tid * 8;
  float vv[8];
  f4_t v0 = (base < n)     ? ((const f4_t*)row)[tid * 2]     : f4_t{0, 0, 0, 0};
  f4_t v1 = (base + 4 < n) ? ((const f4_t*)row)[tid * 2 + 1] : f4_t{0, 0, 0, 0};
#pragma unroll
  for (int e = 0; e < 4; ++e) { vv[e] = v0[e]; vv[4 + e] = v1[e]; }
  float mx = -INFINITY;
#pragma unroll
  for (int e = 0; e < 8; ++e) {
    if (base + e >= n) vv[e] = -INFINITY;
    mx = fmaxf(mx, vv[e]);
  }
  for (int off = 32; off; off >>= 1) mx = fmaxf(mx, __shfl_xor(mx, off));
  __shared__ float red[8];
  const int lane = tid & 63, wid = tid >> 6;
  if (lane == 0) red[wid] = mx;
  __syncthreads();
  if (tid == 0) {
    float m = fmaxf(fmaxf(red[0], red[1]), fmaxf(red[2], red[3]));
    red[4] = m;
  }
  __syncthreads();
  mx = red[4];
  float sum = 0.0f;
#pragma unroll
  for (int e = 0; e < 8; ++e) {
    vv[e] = (base + e < n) ? __expf(vv[e] - mx) : 0.0f;
    sum += vv[e];
  }
  for (int off = 32; off; off >>= 1) sum += __shfl_xor(sum, off);
  __syncthreads();
  if (lane == 0) red[wid] = sum;
  __syncthreads();
  if (tid == 0) red[5] = 1.0f / (red[0] + red[1] + red[2] + red[3]);
  __syncthreads();
  const float inv = red[5];
  f4_t o0, o1;
  h8_t hv;
#pragma unroll
  for (int e = 0; e < 8; ++e) {
    const float a = vv[e] * inv;  // zero beyond n
    if (e < 4) o0[e] = a; else o1[e - 4] = a;
    hv[e] = (half_t)a;
  }
  ((f4_t*)row)[tid * 2] = o0;       // full-row writes: zeros beyond the
  ((f4_t*)row)[tid * 2 + 1] = o1;   // causal boundary are required output
  ((h8_t*)hrow)[tid] = hv;
}

// ---------- Y = A * V (causal K), epilogue Out0 = X + Y, heavy-first ----------
__global__ __launch_bounds__(NT) void gemm_y_kernel(
    const half_t* __restrict__ Ah, const half_t* __restrict__ Vt,
    const float* __restrict__ X, float* __restrict__ Out) {
  __shared__ half_t sm[2 * 2 * BM * BK];  // 32 KB
  const int tn = blockIdx.x, bi = blockIdx.z;
  const int tm = (kS / BM - 1) - blockIdx.y;  // heavy-first
  const size_t abase = ((size_t)bi * kS + (size_t)tm * BM) * kS;
  const size_t bbase = ((size_t)bi * kD + (size_t)tn * BN) * kS;
  f16x acc[2] = {};
  gemm_core<false>(Ah + abase, nullptr, kS, Vt + bbase, nullptr, kS,
                   (tm + 1) * BM / BK, sm, acc);
  const size_t obase = (size_t)bi * kS * kD;
  const int lane = threadIdx.x & 63;
  const int wid = threadIdx.x >> 6;
  const int wm = (wid >> 2) * 64, wn = (wid & 3) * 32;
  const int r32 = lane & 31, hi = lane >> 5;
#pragma unroll
  for (int t = 0; t < 2; ++t)
#pragma unroll
    for (int g = 0; g < 16; ++g) {
      const int rl = (g & 3) + 8 * (g >> 2) + 4 * hi;
      const size_t row = (size_t)tm * BM + wm + t * 32 + rl;
      const size_t col = (size_t)tn * BN + wn + r32;
      const size_t idx = obase + row * kD + col;
      Out[idx] = X[idx] + acc[t][g];
    }
}

// ---------- merged prep: X hi/lo split + WQK hi/lo split + WOV convert ----------
__global__ __launch_bounds__(256) void prep_kernel(const float* __restrict__ X,
                                                   const float* __restrict__ WQK,
                                                   const float* __restrict__ WOV,
                                                   half_t* __restrict__ Xhi,
                                                   half_t* __restrict__ Xlo,
                                                   half_t* __restrict__ Whi,
                                                   half_t* __restrict__ Wlo,
                                                   half_t* __restrict__ WVh) {
  constexpr int nX4 = kB * kS * kD / 4;  // 2097152
  constexpr int nW4 = kD * kD / 4;       // 262144
  const int i = blockIdx.x * 256 + threadIdx.x;
  const float* src;
  half_t* hi;
  half_t* lo;
  int idx;
  if (i < nX4) { src = X; hi = Xhi; lo = Xlo; idx = i; }
  else if (i < nX4 + nW4) { src = WQK; hi = Whi; lo = Wlo; idx = i - nX4; }
  else { src = WOV; hi = WVh; lo = nullptr; idx = i - nX4 - nW4; }
  const float4 v = ((const float4*)src)[idx];
  const float vvv[4] = {v.x, v.y, v.z, v.w};
  h4_t h, l;
#pragma unroll
  for (int j = 0; j < 4; ++j) {
    const half_t hh = (half_t)vvv[j];
    h[j] = hh;
    l[j] = (half_t)(vvv[j] - (float)hh);
  }
  ((h4_t*)hi)[idx] = h;
  if (lo) ((h4_t*)lo)[idx] = l;
}

extern "C" void kernel_launch(void* const* d_in, const int* in_sizes, int n_in,
                              void* d_out, int out_size, void* d_ws, size_t ws_size,
                              hipStream_t stream) {
  const float* X   = (const float*)d_in[0];
  // d_in[1] = causal mask: deterministic (tril), recomputed on the fly — unused
  const float* WQK = (const float*)d_in[2];
  const float* WOV = (const float*)d_in[3];

  constexpr size_t nX = (size_t)kB * kS * kD;   // 8388608
  constexpr size_t nW = (size_t)kD * kD;        // 1048576
  constexpr size_t nA = (size_t)kB * kS * kS;   // 16777216

  float* out0 = (float*)d_out;        // X + Y
  float* outA = out0 + nX;            // A (also used as raw-score scratch)

  // workspace layout (fp16 elements)
  half_t* ws = (half_t*)d_ws;
  half_t* Xhi = ws; ws += nX;
  half_t* Xlo = ws; ws += nX;
  half_t* Qhi = ws; ws += nX;
  half_t* Qlo = ws; ws += nX;
  half_t* Whi = ws; ws += nW;
  half_t* Wlo = ws; ws += nW;
  half_t* WVh = ws; ws += nW;
  half_t* Vt  = ws; ws += nX;
  half_t* Ah  = ws; ws += nA;
  const size_t need_bytes = (size_t)((char*)ws - (char*)d_ws);
  if (ws_size < need_bytes) return;  // workspace too small: fail loudly (stub output)

  constexpr int prep_items = (int)(nX / 4 + 2 * (nW / 4));
  prep_kernel<<<prep_items / 256, 256, 0, stream>>>(X, WQK, WOV, Xhi, Xlo, Whi, Wlo, WVh);

  gemm_qv_kernel<<<1024, NT, 0, stream>>>(Xhi, Xlo, Whi, Wlo, WVh, Qhi, Qlo, Vt);
  gemm_score_kernel<<<dim3(kS / BN, kS / BM, kB), NT, 0, stream>>>(Qhi, Qlo, Xhi, Xlo, outA);
  softmax_kernel<<<kB * kS, 256, 0, stream>>>(outA, Ah);
  gemm_y_kernel<<<dim3(kD / BN, kS / BM, kB), NT, 0, stream>>>(Ah, Vt, X, out0);
}

// Round 11
// 384.926 us; speedup vs baseline: 1.1131x; 1.1131x over previous
//
#include <hip/hip_runtime.h>
#include <hip/hip_fp16.h>
#include <math.h>

typedef _Float16 half_t;
typedef _Float16 h8_t __attribute__((ext_vector_type(8)));
typedef _Float16 h4_t __attribute__((ext_vector_type(4)));
typedef float f4_t __attribute__((ext_vector_type(4)));

#define MFMA16(a, b, c) __builtin_amdgcn_mfma_f32_16x16x32_f16(a, b, c, 0, 0, 0)

static constexpr int kB = 4;
static constexpr int kS = 2048;
static constexpr int kD = 1024;
static constexpr int BM = 128;
static constexpr int BN = 128;
static constexpr int BK = 32;   // LDS leading dim (halves): 64B rows, lane-contiguous
static constexpr int NT = 512;  // 8 waves/block: 64x32 output sub-tile per wave

// ---------- async 16B global->LDS (gfx950 direct-to-LDS path) ----------
__device__ __forceinline__ void gload16(const half_t* g, half_t* l) {
  __builtin_amdgcn_global_load_lds(
      (const __attribute__((address_space(1))) void*)g,
      (__attribute__((address_space(3))) void*)l, 16, 0, 0);
}

// ---------- stage one BMxBK fp16 tile into LDS [BM][BK], bank-swizzled ----------
// 512 threads: thread t covers row r = t>>2, 16B granule (t&3).
// LDS dest stays LINEAR (global_load_lds: wave base + lane*16B); the global
// SOURCE column is XOR-swizzled by ((r>>1)&3) granules, and fragment reads
// apply the same XOR (2-way bank aliasing = free; was 8-way).
// NOTE (R10 lesson): matched to the 16x16 fragment read (16 distinct
// rows/wave). 32x32 reads (32 rows/wave) alias 4-way -> 9.4M conflicts.
__device__ __forceinline__ void stage_tile(half_t* __restrict__ sm,
                                           const half_t* __restrict__ g, int ld) {
  const int t = threadIdx.x;
  const int r = t >> 2;
  const int g8 = (t & 3) * 8;
  const int c = g8 ^ (((r >> 1) & 3) << 3);  // pre-swizzled source col
  gload16(&g[(size_t)r * ld + c], &sm[r * BK + g8]);
}

template <bool SPLIT>
__device__ __forceinline__ void stage_all(half_t* buf, const half_t* Ahi,
                                          const half_t* Alo, int lda,
                                          const half_t* Bhi, const half_t* Blo,
                                          int ldb, size_t ko) {
  stage_tile(buf, Ahi + ko, lda);
  stage_tile(buf + BM * BK, Bhi + ko, ldb);
  if (SPLIT) {
    stage_tile(buf + 2 * BM * BK, Alo + ko, lda);
    stage_tile(buf + 3 * BM * BK, Blo + ko, ldb);
  }
}

// ---------- NT GEMM core, 8-wave, 2-phase double-buffered (R3 champion) ----------
// C[128,128] += A[128,K] * B[128,K]^T, optional hi/lo split (3-term product).
// Wave wid owns rows [(wid>>2)*64, +64) x cols [(wid&3)*32, +32): acc[4][2].
// Schedule per K-step: stage(nxt) -> frag reads -> MFMA -> vmcnt(0) ->
// s_barrier -> swap. One raw barrier per step (prefetch stays in flight
// during the MFMA cluster; __syncthreads would drain it first).
template <bool SPLIT>
__device__ __forceinline__ void gemm_core(const half_t* __restrict__ Ahi,
                                          const half_t* __restrict__ Alo, int lda,
                                          const half_t* __restrict__ Bhi,
                                          const half_t* __restrict__ Blo, int ldb,
                                          int k_iters, half_t* sm, f4_t (&acc)[4][2]) {
  constexpr int BUFSZ = (SPLIT ? 4 : 2) * BM * BK;
  const int lane = threadIdx.x & 63;
  const int wid = threadIdx.x >> 6;        // 0..7
  const int wm = (wid >> 2) * 64;          // 0, 64
  const int wn = (wid & 3) * 32;           // 0, 32, 64, 96
  const int fr = lane & 15;                                       // fragment row
  const int fk = (((lane >> 4) * 8) ^ (((lane >> 1) & 3) << 3));  // swizzled k-off

  half_t* cur = sm;
  half_t* nxt = sm + BUFSZ;

  stage_all<SPLIT>(cur, Ahi, Alo, lda, Bhi, Blo, ldb, 0);
  asm volatile("s_waitcnt vmcnt(0)" ::: "memory");
  __builtin_amdgcn_s_barrier();

  for (int kk = 0; kk < k_iters; ++kk) {
    if (kk + 1 < k_iters)
      stage_all<SPLIT>(nxt, Ahi, Alo, lda, Bhi, Blo, ldb, (size_t)(kk + 1) * BK);
    const half_t* sAh = cur;
    const half_t* sBh = cur + BM * BK;
    const half_t* sAl = cur + 2 * BM * BK;
    const half_t* sBl = cur + 3 * BM * BK;
    h8_t a[4], b[2], al[4], bl[2];
#pragma unroll
    for (int i = 0; i < 4; ++i) {
      a[i] = *(const h8_t*)&sAh[(wm + i * 16 + fr) * BK + fk];
      if (SPLIT) al[i] = *(const h8_t*)&sAl[(wm + i * 16 + fr) * BK + fk];
    }
#pragma unroll
    for (int j = 0; j < 2; ++j) {
      b[j] = *(const h8_t*)&sBh[(wn + j * 16 + fr) * BK + fk];
      if (SPLIT) bl[j] = *(const h8_t*)&sBl[(wn + j * 16 + fr) * BK + fk];
    }
#pragma unroll
    for (int i = 0; i < 4; ++i)
#pragma unroll
      for (int j = 0; j < 2; ++j) {
        acc[i][j] = MFMA16(a[i], b[j], acc[i][j]);
        if (SPLIT) {
          acc[i][j] = MFMA16(a[i], bl[j], acc[i][j]);
          acc[i][j] = MFMA16(al[i], b[j], acc[i][j]);
        }
      }
    asm volatile("s_waitcnt vmcnt(0)" ::: "memory");
    __builtin_amdgcn_s_barrier();
    half_t* t = cur; cur = nxt; nxt = t;
  }
}

// ---------- Q = X * WQK^T (split, fp32-accurate), write Qhi/Qlo fp16 split ----------
__global__ __launch_bounds__(NT) void gemm_q_kernel(
    const half_t* __restrict__ Xhi, const half_t* __restrict__ Xlo,
    const half_t* __restrict__ Whi, const half_t* __restrict__ Wlo,
    half_t* __restrict__ Qhi, half_t* __restrict__ Qlo) {
  __shared__ half_t sm[2 * 4 * BM * BK];  // 64 KB: double-buffered split tiles
  const size_t arow = (size_t)blockIdx.y * BM;
  const size_t brow = (size_t)blockIdx.x * BN;
  f4_t acc[4][2] = {};
  gemm_core<true>(Xhi + arow * kD, Xlo + arow * kD, kD,
                  Whi + brow * kD, Wlo + brow * kD, kD, kD / BK, sm, acc);
  const int lane = threadIdx.x & 63;
  const int wid = threadIdx.x >> 6;
  const int wm = (wid >> 2) * 64, wn = (wid & 3) * 32;
  const int c16 = lane & 15, r4 = (lane >> 4) * 4;
#pragma unroll
  for (int i = 0; i < 4; ++i)
#pragma unroll
    for (int j = 0; j < 2; ++j)
#pragma unroll
      for (int r = 0; r < 4; ++r) {
        const size_t row = arow + wm + i * 16 + r4 + r;
        const size_t col = brow + wn + j * 16 + c16;
        const float q = acc[i][j][r];
        const half_t qh = (half_t)q;
        const half_t ql = (half_t)(q - (float)qh);
        const size_t idx = row * kD + col;
        Qhi[idx] = qh;
        Qlo[idx] = ql;
      }
}

// ---------- V = X * WOV^T (single-pass fp16), stored transposed: Vt[b][e][t] ----------
__global__ __launch_bounds__(NT) void gemm_v_kernel(
    const half_t* __restrict__ Xhi, const half_t* __restrict__ Whi,
    half_t* __restrict__ Vt) {
  __shared__ half_t sm[2 * 2 * BM * BK];  // 32 KB double-buffered
  const size_t arow = (size_t)blockIdx.y * BM;
  const size_t brow = (size_t)blockIdx.x * BN;
  f4_t acc[4][2] = {};
  gemm_core<false>(Xhi + arow * kD, nullptr, kD, Whi + brow * kD, nullptr, kD,
                   kD / BK, sm, acc);
  const int lane = threadIdx.x & 63;
  const int wid = threadIdx.x >> 6;
  const int wm = (wid >> 2) * 64, wn = (wid & 3) * 32;
  const int c16 = lane & 15, r4 = (lane >> 4) * 4;
#pragma unroll
  for (int i = 0; i < 4; ++i)
#pragma unroll
    for (int j = 0; j < 2; ++j)
#pragma unroll
      for (int r = 0; r < 4; ++r) {
        const size_t row = arow + wm + i * 16 + r4 + r;  // global 0..8191
        const size_t col = brow + wn + j * 16 + c16;     // e: 0..1023
        const size_t bi = row >> 11;
        const size_t s = row & 2047;
        Vt[bi * (size_t)kD * kS + col * kS + s] = (half_t)acc[i][j][r];
      }
}

// ---------- Sc = 32 * Q * X^T (2D grid, early-return, no swizzle) ----------
__global__ __launch_bounds__(NT) void gemm_score_kernel(
    const half_t* __restrict__ Qhi, const half_t* __restrict__ Qlo,
    const half_t* __restrict__ Xhi, const half_t* __restrict__ Xlo,
    float* __restrict__ Sc) {
  const int tn = blockIdx.x, tm = blockIdx.y, bi = blockIdx.z;
  if (tn > tm) return;  // fully masked tile: softmax never reads it
  __shared__ half_t sm[2 * 4 * BM * BK];  // 64 KB
  const size_t arow = (size_t)bi * kS + (size_t)tm * BM;
  const size_t brow = (size_t)bi * kS + (size_t)tn * BN;
  f4_t acc[4][2] = {};
  gemm_core<true>(Qhi + arow * kD, Qlo + arow * kD, kD,
                  Xhi + brow * kD, Xlo + brow * kD, kD, kD / BK, sm, acc);
  float* out = Sc + (size_t)bi * kS * kS;
  const int lane = threadIdx.x & 63;
  const int wid = threadIdx.x >> 6;
  const int wm = (wid >> 2) * 64, wn = (wid & 3) * 32;
  const int c16 = lane & 15, r4 = (lane >> 4) * 4;
#pragma unroll
  for (int i = 0; i < 4; ++i)
#pragma unroll
    for (int j = 0; j < 2; ++j)
#pragma unroll
      for (int r = 0; r < 4; ++r) {
        const int row = tm * BM + wm + i * 16 + r4 + r;
        const int col = tn * BN + wn + j * 16 + c16;
        out[(size_t)row * kS + col] = 32.0f * acc[i][j][r];
      }
}

// ---------- row softmax (causal), causal-prefix reads, vectorized I/O ----------
__global__ __launch_bounds__(256) void softmax_kernel(float* __restrict__ A,
                                                      half_t* __restrict__ Ah) {
  const int rgl = blockIdx.x;  // 0..8191
  const int s = rgl & 2047;
  float* row = A + (size_t)rgl * kS;
  half_t* hrow = Ah + (size_t)rgl * kS;
  const int tid = threadIdx.x;
  const int n = s + 1;
  const int base = tid * 8;
  float vv[8];
  f4_t v0 = (base < n)     ? ((const f4_t*)row)[tid * 2]     : f4_t{0, 0, 0, 0};
  f4_t v1 = (base + 4 < n) ? ((const f4_t*)row)[tid * 2 + 1] : f4_t{0, 0, 0, 0};
#pragma unroll
  for (int e = 0; e < 4; ++e) { vv[e] = v0[e]; vv[4 + e] = v1[e]; }
  float mx = -INFINITY;
#pragma unroll
  for (int e = 0; e < 8; ++e) {
    if (base + e >= n) vv[e] = -INFINITY;
    mx = fmaxf(mx, vv[e]);
  }
  for (int off = 32; off; off >>= 1) mx = fmaxf(mx, __shfl_xor(mx, off));
  __shared__ float red[8];
  const int lane = tid & 63, wid = tid >> 6;
  if (lane == 0) red[wid] = mx;
  __syncthreads();
  if (tid == 0) {
    float m = fmaxf(fmaxf(red[0], red[1]), fmaxf(red[2], red[3]));
    red[4] = m;
  }
  __syncthreads();
  mx = red[4];
  float sum = 0.0f;
#pragma unroll
  for (int e = 0; e < 8; ++e) {
    vv[e] = (base + e < n) ? __expf(vv[e] - mx) : 0.0f;
    sum += vv[e];
  }
  for (int off = 32; off; off >>= 1) sum += __shfl_xor(sum, off);
  __syncthreads();
  if (lane == 0) red[wid] = sum;
  __syncthreads();
  if (tid == 0) red[5] = 1.0f / (red[0] + red[1] + red[2] + red[3]);
  __syncthreads();
  const float inv = red[5];
  f4_t o0, o1;
  h8_t hv;
#pragma unroll
  for (int e = 0; e < 8; ++e) {
    const float a = vv[e] * inv;  // zero beyond n
    if (e < 4) o0[e] = a; else o1[e - 4] = a;
    hv[e] = (half_t)a;
  }
  ((f4_t*)row)[tid * 2] = o0;       // full-row writes: zeros beyond the
  ((f4_t*)row)[tid * 2 + 1] = o1;   // causal boundary are required output
  ((h8_t*)hrow)[tid] = hv;
}

// ---------- Y = A * V (causal K), epilogue Out0 = X + Y, heavy-first ----------
__global__ __launch_bounds__(NT) void gemm_y_kernel(
    const half_t* __restrict__ Ah, const half_t* __restrict__ Vt,
    const float* __restrict__ X, float* __restrict__ Out) {
  __shared__ half_t sm[2 * 2 * BM * BK];  // 32 KB
  const int tn = blockIdx.x, bi = blockIdx.z;
  const int tm = (kS / BM - 1) - blockIdx.y;  // heavy-first
  const size_t abase = ((size_t)bi * kS + (size_t)tm * BM) * kS;
  const size_t bbase = ((size_t)bi * kD + (size_t)tn * BN) * kS;
  f4_t acc[4][2] = {};
  gemm_core<false>(Ah + abase, nullptr, kS, Vt + bbase, nullptr, kS,
                   (tm + 1) * BM / BK, sm, acc);
  const size_t obase = (size_t)bi * kS * kD;
  const int lane = threadIdx.x & 63;
  const int wid = threadIdx.x >> 6;
  const int wm = (wid >> 2) * 64, wn = (wid & 3) * 32;
  const int c16 = lane & 15, r4 = (lane >> 4) * 4;
#pragma unroll
  for (int i = 0; i < 4; ++i)
#pragma unroll
    for (int j = 0; j < 2; ++j)
#pragma unroll
      for (int r = 0; r < 4; ++r) {
        const size_t row = (size_t)tm * BM + wm + i * 16 + r4 + r;
        const size_t col = (size_t)tn * BN + wn + j * 16 + c16;
        const size_t idx = obase + row * kD + col;
        Out[idx] = X[idx] + acc[i][j][r];
      }
}

// ---------- merged prep: X hi/lo split + WQK hi/lo split + WOV convert ----------
__global__ __launch_bounds__(256) void prep_kernel(const float* __restrict__ X,
                                                   const float* __restrict__ WQK,
                                                   const float* __restrict__ WOV,
                                                   half_t* __restrict__ Xhi,
                                                   half_t* __restrict__ Xlo,
                                                   half_t* __restrict__ Whi,
                                                   half_t* __restrict__ Wlo,
                                                   half_t* __restrict__ WVh) {
  constexpr int nX4 = kB * kS * kD / 4;  // 2097152
  constexpr int nW4 = kD * kD / 4;       // 262144
  const int i = blockIdx.x * 256 + threadIdx.x;
  const float* src;
  half_t* hi;
  half_t* lo;
  int idx;
  if (i < nX4) { src = X; hi = Xhi; lo = Xlo; idx = i; }
  else if (i < nX4 + nW4) { src = WQK; hi = Whi; lo = Wlo; idx = i - nX4; }
  else { src = WOV; hi = WVh; lo = nullptr; idx = i - nX4 - nW4; }
  const float4 v = ((const float4*)src)[idx];
  const float vvv[4] = {v.x, v.y, v.z, v.w};
  h4_t h, l;
#pragma unroll
  for (int j = 0; j < 4; ++j) {
    const half_t hh = (half_t)vvv[j];
    h[j] = hh;
    l[j] = (half_t)(vvv[j] - (float)hh);
  }
  ((h4_t*)hi)[idx] = h;
  if (lo) ((h4_t*)lo)[idx] = l;
}

extern "C" void kernel_launch(void* const* d_in, const int* in_sizes, int n_in,
                              void* d_out, int out_size, void* d_ws, size_t ws_size,
                              hipStream_t stream) {
  const float* X   = (const float*)d_in[0];
  // d_in[1] = causal mask: deterministic (tril), recomputed on the fly — unused
  const float* WQK = (const float*)d_in[2];
  const float* WOV = (const float*)d_in[3];

  constexpr size_t nX = (size_t)kB * kS * kD;   // 8388608
  constexpr size_t nW = (size_t)kD * kD;        // 1048576
  constexpr size_t nA = (size_t)kB * kS * kS;   // 16777216

  float* out0 = (float*)d_out;        // X + Y
  float* outA = out0 + nX;            // A (also used as raw-score scratch)

  // workspace layout (fp16 elements)
  half_t* ws = (half_t*)d_ws;
  half_t* Xhi = ws; ws += nX;
  half_t* Xlo = ws; ws += nX;
  half_t* Qhi = ws; ws += nX;
  half_t* Qlo = ws; ws += nX;
  half_t* Whi = ws; ws += nW;
  half_t* Wlo = ws; ws += nW;
  half_t* WVh = ws; ws += nW;
  half_t* Vt  = ws; ws += nX;
  half_t* Ah  = ws; ws += nA;
  const size_t need_bytes = (size_t)((char*)ws - (char*)d_ws);
  if (ws_size < need_bytes) return;  // workspace too small: fail loudly (stub output)

  constexpr int prep_items = (int)(nX / 4 + 2 * (nW / 4));
  prep_kernel<<<prep_items / 256, 256, 0, stream>>>(X, WQK, WOV, Xhi, Xlo, Whi, Wlo, WVh);

  gemm_q_kernel<<<dim3(kD / BN, kB * kS / BM), NT, 0, stream>>>(Xhi, Xlo, Whi, Wlo, Qhi, Qlo);
  gemm_v_kernel<<<dim3(kD / BN, kB * kS / BM), NT, 0, stream>>>(Xhi, WVh, Vt);
  gemm_score_kernel<<<dim3(kS / BN, kS / BM, kB), NT, 0, stream>>>(Qhi, Qlo, Xhi, Xlo, outA);
  softmax_kernel<<<kB * kS, 256, 0, stream>>>(outA, Ah);
  gemm_y_kernel<<<dim3(kD / BN, kS / BM, kB), NT, 0, stream>>>(Ah, Vt, X, out0);
}